// Round 12
// baseline (847.763 us; speedup 1.0000x reference)
//
#include <hip/hip_runtime.h>
#include <hip/hip_bf16.h>
#include <math.h>
#include <stdint.h>

// Problem constants (B=4, S=2048, H=1024, I=4096, E=8, K=2)
#define TOKENS 8192
#define HD 1024
#define ID 4096
#define NE 8
#define RMAX 18432   // 16384 + 8*256 worst-case padded rows (experts padded to 256)
#define MAXT 72      // RMAX/256 max M-tiles
#define NG1 2304     // gemm1 gemm blocks (MAXT*32)
#define CVTD_BLOCKS 8192  // convert-Wd tail blocks in gemm1 dispatch (512 thr * 8 elem)
#define RTR_BLOCKS 2048   // router blocks in router_conv dispatch
#define CVTGU_BLOCKS 32768
#define NWG2 576          // gemm2 logical tiles (MAXT*8)
#define GRID2 512         // gemm2 persistent grid

typedef __attribute__((ext_vector_type(8))) short short8v;
typedef __attribute__((ext_vector_type(4))) float f32x4;

typedef const __attribute__((address_space(1))) unsigned int* gas_u32p;
typedef __attribute__((address_space(3))) unsigned int* las_u32p;

__device__ __forceinline__ void stage16(const void* g, void* l) {
  __builtin_amdgcn_global_load_lds((gas_u32p)g, (las_u32p)l, 16, 0, 0);
}

#define BARRIER asm volatile("s_barrier" ::: "memory")
#define WAITLGKM asm volatile("s_waitcnt lgkmcnt(0)" ::: "memory")
#define VMC0 asm volatile("s_waitcnt vmcnt(0)" ::: "memory")
#define VMC6 asm volatile("s_waitcnt vmcnt(6)" ::: "memory")

// convert 8 consecutive fp32 (2 NT vector loads) -> 8 bf16 packed in int4
__device__ __forceinline__ int4 cvt8_nt(const float* __restrict__ src) {
  f32x4 a = __builtin_nontemporal_load((const f32x4*)src);
  f32x4 b = __builtin_nontemporal_load(((const f32x4*)src) + 1);
  union { __hip_bfloat16 h[8]; int4 v; } u;
  u.h[0] = __float2bfloat16(a.x); u.h[1] = __float2bfloat16(a.y);
  u.h[2] = __float2bfloat16(a.z); u.h[3] = __float2bfloat16(a.w);
  u.h[4] = __float2bfloat16(b.x); u.h[5] = __float2bfloat16(b.y);
  u.h[6] = __float2bfloat16(b.z); u.h[7] = __float2bfloat16(b.w);
  return u.v;
}

// ---------------- router (blocks 0..2047) + convert gate/up (tail blocks) ----------------
__global__ __launch_bounds__(256) void router_conv_kernel(
    const float* __restrict__ h, const float* __restrict__ rw,
    __hip_bfloat16* __restrict__ hx, int* __restrict__ tidx,
    float* __restrict__ tw, int* __restrict__ cnt,
    const float* __restrict__ gw, const float* __restrict__ uw,
    __hip_bfloat16* __restrict__ wgu) {
  if (blockIdx.x >= RTR_BLOCKS) {
    int cb = blockIdx.x - RTR_BLOCKS;       // [0, 32768)
    int r = cb >> 14;                        // 2 regions x 16384 blocks
    const float* src = (r == 0) ? gw : uw;
    __hip_bfloat16* dst = wgu + (size_t)r * ((size_t)NE * ID * HD);
    size_t i = (((size_t)(cb & 16383)) * 256 + threadIdx.x) * 8;
    *(int4*)(dst + i) = cvt8_nt(src + i);
    return;
  }
  int wid = threadIdx.x >> 6, lane = threadIdx.x & 63;
  int t = blockIdx.x * 4 + wid;
  const f32x4* h4 = (const f32x4*)(h + (size_t)t * HD);
  float x[16];
  {
    f32x4 xa = __builtin_nontemporal_load(h4 + lane * 4 + 0);
    f32x4 xb = __builtin_nontemporal_load(h4 + lane * 4 + 1);
    f32x4 xc = __builtin_nontemporal_load(h4 + lane * 4 + 2);
    f32x4 xd = __builtin_nontemporal_load(h4 + lane * 4 + 3);
    x[0] = xa.x; x[1] = xa.y; x[2] = xa.z; x[3] = xa.w;
    x[4] = xb.x; x[5] = xb.y; x[6] = xb.z; x[7] = xb.w;
    x[8] = xc.x; x[9] = xc.y; x[10] = xc.z; x[11] = xc.w;
    x[12] = xd.x; x[13] = xd.y; x[14] = xd.z; x[15] = xd.w;
  }
  union { __hip_bfloat16 hb[16]; int4 v[2]; } u;
#pragma unroll
  for (int j = 0; j < 16; j++) u.hb[j] = __float2bfloat16(x[j]);
  {
    int4* hxp = (int4*)(hx + (size_t)t * HD + lane * 16);
    hxp[0] = u.v[0]; hxp[1] = u.v[1];
  }
  double acc[NE];
#pragma unroll
  for (int e = 0; e < NE; e++) {
    const float4* w4 = (const float4*)(rw + e * HD);
    float4 wa = w4[lane * 4 + 0], wb = w4[lane * 4 + 1], wc = w4[lane * 4 + 2], wd = w4[lane * 4 + 3];
    double s = 0.0;
    s += (double)x[0] * wa.x + (double)x[1] * wa.y + (double)x[2] * wa.z + (double)x[3] * wa.w;
    s += (double)x[4] * wb.x + (double)x[5] * wb.y + (double)x[6] * wb.z + (double)x[7] * wb.w;
    s += (double)x[8] * wc.x + (double)x[9] * wc.y + (double)x[10] * wc.z + (double)x[11] * wc.w;
    s += (double)x[12] * wd.x + (double)x[13] * wd.y + (double)x[14] * wd.z + (double)x[15] * wd.w;
    acc[e] = s;
  }
#pragma unroll
  for (int off = 32; off >= 1; off >>= 1)
#pragma unroll
    for (int e = 0; e < NE; e++) acc[e] += __shfl_xor(acc[e], off, 64);
  if (lane == 0) {
    int i0 = 0; double l0 = acc[0];
#pragma unroll
    for (int e = 1; e < NE; e++) if (acc[e] > l0) { l0 = acc[e]; i0 = e; }
    int i1 = -1; double l1 = -1.0e300;
#pragma unroll
    for (int e = 0; e < NE; e++) if (e != i0 && acc[e] > l1) { l1 = acc[e]; i1 = e; }
    double r = exp(l1 - l0);  // <= 1
    float w0 = (float)(1.0 / (1.0 + r));
    float w1 = (float)(r / (1.0 + r));
    tidx[t * 2 + 0] = i0; tidx[t * 2 + 1] = i1;
    tw[t * 2 + 0] = w0;  tw[t * 2 + 1] = w1;
    atomicAdd(&cnt[i0], 1); atomicAdd(&cnt[i1], 1);
  }
}

// ---------------- offsets scan (pad each expert to 256 rows) ----------------
__global__ void scan_kernel(const int* __restrict__ cnt, int* __restrict__ ofs, int* __restrict__ cnt2) {
  if (threadIdx.x == 0) {
    int a = 0;
    for (int e = 0; e < NE; e++) { ofs[e] = a; a += (cnt[e] + 255) & ~255; }
    ofs[NE] = a;
  }
  if (threadIdx.x < NE) cnt2[threadIdx.x] = 0;
}

// ---------------- scatter token -> expert row lists (+ slot map) ----------------
__global__ __launch_bounds__(256) void scatter_kernel(
    const int* __restrict__ tidx, const int* __restrict__ ofs, int* __restrict__ cnt2,
    int* __restrict__ rowmap, int* __restrict__ slots) {
  int t = blockIdx.x * 256 + threadIdx.x;
#pragma unroll
  for (int k = 0; k < 2; k++) {
    int e = tidx[t * 2 + k];
    int pos = atomicAdd(&cnt2[e], 1);
    int row = ofs[e] + pos;
    rowmap[row] = t;
    slots[t * 2 + k] = row;
  }
}

// MFMA quadrant: 4 m-frags x 2 n-frags x 2 kk = 16 MFMA
#define MFMAQ(ACC, MO, NO, AF, BF)                                                         \
  { _Pragma("unroll") for (int m_ = 0; m_ < 4; m_++)                                       \
    _Pragma("unroll") for (int n_ = 0; n_ < 2; n_++)                                       \
    _Pragma("unroll") for (int k_ = 0; k_ < 2; k_++)                                       \
      ACC[(MO) + m_][(NO) + n_] = __builtin_amdgcn_mfma_f32_16x16x32_bf16(                 \
          AF[m_][k_], BF[n_][k_], ACC[(MO) + m_][(NO) + n_], 0, 0, 0); }

// 16 MFMA, one k-half: 4m x 4n
#define MFMA16K(ACC, AF, BF)                                                               \
  { _Pragma("unroll") for (int m_ = 0; m_ < 4; m_++)                                       \
    _Pragma("unroll") for (int n_ = 0; n_ < 4; n_++)                                       \
      ACC[m_][n_] = __builtin_amdgcn_mfma_f32_16x16x32_bf16(                               \
          AF[m_], BF[n_], ACC[m_][n_], 0, 0, 0); }

// =================== GEMM1 (fused gate+up+silu), 256x128 tile, 8-phase ===================
// R6-proven. tm-fastest tile order; Wd-convert tail blocks (NT load of read-once dw).
__global__ __launch_bounds__(512, 2) void gemm1_kernel(
    const __hip_bfloat16* __restrict__ hx, const __hip_bfloat16* __restrict__ Wg,
    const __hip_bfloat16* __restrict__ Wu, const int* __restrict__ rowmap,
    const int* __restrict__ ofs, const __hip_bfloat16* __restrict__ zrow,
    __hip_bfloat16* __restrict__ act,
    const float* __restrict__ dwsrc, __hip_bfloat16* __restrict__ wd) {
  const int tid = threadIdx.x;
  if (blockIdx.x >= NG1) {
    size_t i = (((size_t)(blockIdx.x - NG1)) * 512 + tid) * 8;
    *(int4*)(wd + i) = cvt8_nt(dwsrc + i);
    return;
  }
  __shared__ __align__(128) char lds[131072];
  int wg0 = blockIdx.x;
  int wg = (wg0 & 7) * (NG1 >> 3) + (wg0 >> 3);  // XCD-chunked swizzle
  const int tm = wg % MAXT, tn = wg / MAXT;      // tm-fastest: chunk shares weights
  const int Rtot = ofs[NE];
  const int row0 = tm * 256;
  if (row0 >= Rtot) return;
  int e = 0;
#pragma unroll
  for (int i = 1; i < NE; i++) e += (row0 >= ofs[i]);
  const int wid = tid >> 6, lane = tid & 63;
  const int wm = wid >> 1, wn = wid & 1;  // 4 M-warps x 2 N-warps
  const int fr = lane & 15, fkE = (lane >> 4) << 3;
  const int wmB = wm * 64, wnB = wn * 64;

  const char* srcA[4]; const char* srcG[2]; const char* srcU[2];
  int ldA[4], ldG[2], ldU[2];
#pragma unroll
  for (int j = 0; j < 4; j++) {
    int d = j * 8192 + tid * 16;
    int row = d >> 7;
    int kb = (d ^ (((d >> 7) & 7) << 4)) & 127;
    int tok = rowmap[row0 + row];
    const __hip_bfloat16* base = (tok >= 0) ? (hx + (size_t)tok * HD) : zrow;
    srcA[j] = (const char*)base + kb;
    ldA[j] = j * 8192 + wid * 1024;
  }
#pragma unroll
  for (int j = 0; j < 2; j++) {
    int d = j * 8192 + tid * 16;
    int row = d >> 7;
    int kb = (d ^ (((d >> 7) & 7) << 4)) & 127;
    srcG[j] = (const char*)(Wg + ((size_t)e * ID + tn * 128 + row) * HD) + kb;
    srcU[j] = (const char*)(Wu + ((size_t)e * ID + tn * 128 + row) * HD) + kb;
    ldG[j] = 32768 + j * 8192 + wid * 1024;
    ldU[j] = 49152 + j * 8192 + wid * 1024;
  }
#define STG_A(j, t, bf) stage16(srcA[j] + (size_t)(t) * 128, (char*)lds + (bf) * 65536 + ldA[j])
#define STG_G(j, t, bf) stage16(srcG[j] + (size_t)(t) * 128, (char*)lds + (bf) * 65536 + ldG[j])
#define STG_U(j, t, bf) stage16(srcU[j] + (size_t)(t) * 128, (char*)lds + (bf) * 65536 + ldU[j])

  auto RD = [&](int bf, int poff, int rowi, int kki) -> short8v {
    int o = ((rowi + fr) << 7) + ((kki << 5) + fkE) * 2;
    o ^= ((o >> 7) & 7) << 4;
    return *(const short8v*)(&lds[bf * 65536 + poff + o]);
  };

  f32x4 accG[4][4], accU[4][4];
#pragma unroll
  for (int m = 0; m < 4; m++)
#pragma unroll
    for (int n = 0; n < 4; n++) { accG[m][n] = (f32x4)(0.0f); accU[m][n] = (f32x4)(0.0f); }

  const int NT = HD / 64;  // 16 K-tiles
#pragma unroll
  for (int j = 0; j < 4; j++) STG_A(j, 0, 0);
#pragma unroll
  for (int j = 0; j < 2; j++) STG_G(j, 0, 0);
#pragma unroll
  for (int j = 0; j < 2; j++) STG_U(j, 0, 0);
#pragma unroll
  for (int j = 0; j < 4; j++) STG_A(j, 1, 1);
#pragma unroll
  for (int j = 0; j < 2; j++) STG_G(j, 1, 1);
  VMC6; BARRIER;

#pragma unroll 1
  for (int I = 0; I < NT / 2; ++I) {
    const int t0 = 2 * I;
    const bool more = (t0 + 2 < NT);
    short8v a[4][2], bA[2][2], bB[2][2];
    // P1
#pragma unroll
    for (int m = 0; m < 4; m++) { a[m][0] = RD(0, 0, wmB + m * 16, 0); a[m][1] = RD(0, 0, wmB + m * 16, 1); }
#pragma unroll
    for (int n = 0; n < 2; n++) { bA[n][0] = RD(0, 32768, wnB + n * 16, 0); bA[n][1] = RD(0, 32768, wnB + n * 16, 1); }
    STG_U(0, t0 + 1, 1); STG_U(1, t0 + 1, 1);
    BARRIER; WAITLGKM;
    __builtin_amdgcn_s_setprio(1); MFMAQ(accG, 0, 0, a, bA); __builtin_amdgcn_s_setprio(0);
    BARRIER;
    // P2
#pragma unroll
    for (int n = 0; n < 2; n++) { bB[n][0] = RD(0, 32768, wnB + 32 + n * 16, 0); bB[n][1] = RD(0, 32768, wnB + 32 + n * 16, 1); }
    if (more) { STG_A(0, t0 + 2, 0); STG_A(1, t0 + 2, 0); }
    BARRIER; WAITLGKM;
    __builtin_amdgcn_s_setprio(1); MFMAQ(accG, 0, 2, a, bB); __builtin_amdgcn_s_setprio(0);
    BARRIER;
    // P3
#pragma unroll
    for (int n = 0; n < 2; n++) { bA[n][0] = RD(0, 49152, wnB + n * 16, 0); bA[n][1] = RD(0, 49152, wnB + n * 16, 1); }
    if (more) { STG_A(2, t0 + 2, 0); STG_A(3, t0 + 2, 0); }
    BARRIER; WAITLGKM;
    __builtin_amdgcn_s_setprio(1); MFMAQ(accU, 0, 0, a, bA); __builtin_amdgcn_s_setprio(0);
    BARRIER;
    // P4
#pragma unroll
    for (int n = 0; n < 2; n++) { bB[n][0] = RD(0, 49152, wnB + 32 + n * 16, 0); bB[n][1] = RD(0, 49152, wnB + 32 + n * 16, 1); }
    if (more) { STG_G(0, t0 + 2, 0); STG_G(1, t0 + 2, 0); }
    BARRIER; WAITLGKM;
    __builtin_amdgcn_s_setprio(1); MFMAQ(accU, 0, 2, a, bB); __builtin_amdgcn_s_setprio(0);
    if (more) { VMC6; } else { VMC0; }
    BARRIER;
    // P5
#pragma unroll
    for (int m = 0; m < 4; m++) { a[m][0] = RD(1, 0, wmB + m * 16, 0); a[m][1] = RD(1, 0, wmB + m * 16, 1); }
#pragma unroll
    for (int n = 0; n < 2; n++) { bA[n][0] = RD(1, 32768, wnB + n * 16, 0); bA[n][1] = RD(1, 32768, wnB + n * 16, 1); }
    if (more) { STG_U(0, t0 + 2, 0); STG_U(1, t0 + 2, 0); }
    BARRIER; WAITLGKM;
    __builtin_amdgcn_s_setprio(1); MFMAQ(accG, 0, 0, a, bA); __builtin_amdgcn_s_setprio(0);
    BARRIER;
    // P6
#pragma unroll
    for (int n = 0; n < 2; n++) { bB[n][0] = RD(1, 32768, wnB + 32 + n * 16, 0); bB[n][1] = RD(1, 32768, wnB + 32 + n * 16, 1); }
    if (more) { STG_A(0, t0 + 3, 1); STG_A(1, t0 + 3, 1); }
    BARRIER; WAITLGKM;
    __builtin_amdgcn_s_setprio(1); MFMAQ(accG, 0, 2, a, bB); __builtin_amdgcn_s_setprio(0);
    BARRIER;
    // P7
#pragma unroll
    for (int n = 0; n < 2; n++) { bA[n][0] = RD(1, 49152, wnB + n * 16, 0); bA[n][1] = RD(1, 49152, wnB + n * 16, 1); }
    if (more) { STG_A(2, t0 + 3, 1); STG_A(3, t0 + 3, 1); }
    BARRIER; WAITLGKM;
    __builtin_amdgcn_s_setprio(1); MFMAQ(accU, 0, 0, a, bA); __builtin_amdgcn_s_setprio(0);
    BARRIER;
    // P8
#pragma unroll
    for (int n = 0; n < 2; n++) { bB[n][0] = RD(1, 49152, wnB + 32 + n * 16, 0); bB[n][1] = RD(1, 49152, wnB + 32 + n * 16, 1); }
    if (more) { STG_G(0, t0 + 3, 1); STG_G(1, t0 + 3, 1); }
    BARRIER; WAITLGKM;
    __builtin_amdgcn_s_setprio(1); MFMAQ(accU, 0, 2, a, bB); __builtin_amdgcn_s_setprio(0);
    if (more) { VMC6; } else { VMC0; }
    BARRIER;
  }
#undef STG_A
#undef STG_G
#undef STG_U

  // epilogue: act = bf16(silu(g)*u) (normal stores — NT-store measured worse in R10)
  const int rb = row0 + wmB + ((lane >> 4) << 2);
  const int cb = tn * 128 + wnB + fr;
#pragma unroll
  for (int m = 0; m < 4; m++)
#pragma unroll
    for (int i = 0; i < 4; i++) {
      int r = rb + m * 16 + i;
      __hip_bfloat16* dst = act + (size_t)r * ID + cb;
#pragma unroll
      for (int n = 0; n < 4; n++) {
        float g = accG[m][n][i], uu = accU[m][n][i];
        float s = g / (1.0f + __expf(-g));
        dst[n * 16] = __float2bfloat16(s * uu);
      }
    }
}

// =================== GEMM2: y = act @ Wd[e]^T, 256x128, 3-buffer, PERSISTENT, bf16 out ===
__global__ __launch_bounds__(512, 2) void gemm2_kernel(
    const __hip_bfloat16* __restrict__ act, const __hip_bfloat16* __restrict__ Wd,
    const int* __restrict__ ofs, __hip_bfloat16* __restrict__ ybuf) {
  __shared__ __align__(128) char lds[147456];
  const int tid = threadIdx.x, wid = tid >> 6, lane = tid & 63;
  const int wm = wid >> 1, wn = wid & 1;
  const int fr = lane & 15, fkE = (lane >> 4) << 3;
  const int wmB = wm * 64, wnB = wn * 64;
  const int Rtot = ofs[NE];

  auto RD = [&](const char* base, int poff, int rowi, int kki) -> short8v {
    int o = ((rowi + fr) << 7) + ((kki << 5) + fkE) * 2;
    o ^= ((o >> 7) & 7) << 4;
    return *(const short8v*)(base + poff + o);
  };

#pragma unroll 1
  for (int wgl = blockIdx.x; wgl < NWG2; wgl += GRID2) {
    int wg = (wgl & 7) * (NWG2 >> 3) + (wgl >> 3);  // XCD-chunked swizzle
    const int tm = wg >> 3, tn = wg & 7;
    const int row0 = tm * 256;
    if (row0 >= Rtot) continue;
    int e = 0;
#pragma unroll
    for (int i = 1; i < NE; i++) e += (row0 >= ofs[i]);

    const char* srcA[4]; const char* srcB[2];
    int ldA[4], ldB[2];
#pragma unroll
    for (int j = 0; j < 4; j++) {
      int d = j * 8192 + tid * 16;
      int row = d >> 7;
      int kb = (d ^ (((d >> 7) & 7) << 4)) & 127;
      srcA[j] = (const char*)(act + (size_t)(row0 + row) * ID) + kb;
      ldA[j] = j * 8192 + wid * 1024;
    }
#pragma unroll
    for (int j = 0; j < 2; j++) {
      int d = j * 8192 + tid * 16;
      int row = d >> 7;
      int kb = (d ^ (((d >> 7) & 7) << 4)) & 127;
      srcB[j] = (const char*)(Wd + ((size_t)e * HD + tn * 128 + row) * ID) + kb;
      ldB[j] = 32768 + j * 8192 + wid * 1024;
    }
#define STG_A2(j, t, q) stage16(srcA[j] + (size_t)(t) * 128, (char*)lds + (q) * 49152 + ldA[j])
#define STG_B2(j, t, q) stage16(srcB[j] + (size_t)(t) * 128, (char*)lds + (q) * 49152 + ldB[j])

    f32x4 acc[4][4];
#pragma unroll
    for (int m = 0; m < 4; m++)
#pragma unroll
      for (int n = 0; n < 4; n++) acc[m][n] = (f32x4)(0.0f);

    const int NT = ID / 64;  // 64 K-tiles
#pragma unroll
    for (int j = 0; j < 4; j++) STG_A2(j, 0, 0);
    STG_B2(0, 0, 0); STG_B2(1, 0, 0);
#pragma unroll
    for (int j = 0; j < 4; j++) STG_A2(j, 1, 1);
    STG_B2(0, 1, 1); STG_B2(1, 1, 1);
    VMC6; BARRIER;

    int q = 0;
#pragma unroll 1
    for (int T = 0; T < NT; ++T) {
      const bool more = (T + 2 < NT);
      const int sq = (q >= 1) ? (q - 1) : 2;  // (q+2)%3
      const char* base = (const char*)lds + q * 49152;
      short8v a0[4], b0[4], a1[4], b1[4];
#pragma unroll
      for (int m = 0; m < 4; m++) a0[m] = RD(base, 0, wmB + m * 16, 0);
#pragma unroll
      for (int n = 0; n < 4; n++) b0[n] = RD(base, 32768, wnB + n * 16, 0);
      if (more) { STG_A2(0, T + 2, sq); STG_A2(1, T + 2, sq); STG_A2(2, T + 2, sq); }
      BARRIER; WAITLGKM;
      __builtin_amdgcn_s_setprio(1); MFMA16K(acc, a0, b0); __builtin_amdgcn_s_setprio(0);
      BARRIER;
#pragma unroll
      for (int m = 0; m < 4; m++) a1[m] = RD(base, 0, wmB + m * 16, 1);
#pragma unroll
      for (int n = 0; n < 4; n++) b1[n] = RD(base, 32768, wnB + n * 16, 1);
      if (more) { STG_A2(3, T + 2, sq); STG_B2(0, T + 2, sq); STG_B2(1, T + 2, sq); }
      BARRIER; WAITLGKM;
      __builtin_amdgcn_s_setprio(1); MFMA16K(acc, a1, b1); __builtin_amdgcn_s_setprio(0);
      if (more) { VMC6; } else { VMC0; }
      BARRIER;
      q = (q == 2) ? 0 : (q + 1);
    }
#undef STG_A2
#undef STG_B2

    const int rb = row0 + wmB + ((lane >> 4) << 2);
    const int cb = tn * 128 + wnB + fr;
#pragma unroll
    for (int m = 0; m < 4; m++)
#pragma unroll
      for (int i = 0; i < 4; i++) {
        int r = rb + m * 16 + i;
        __hip_bfloat16* dst = ybuf + (size_t)r * HD + cb;
#pragma unroll
        for (int n = 0; n < 4; n++) dst[n * 16] = __float2bfloat16(acc[m][n][i]);
      }
    BARRIER;  // LDS safe before next persistent tile's prologue
  }
}

// ---------------- combine: out[t] = w0*y[slot0] + w1*y[slot1] (bf16 y) ----------------
__global__ __launch_bounds__(256) void combine_kernel(
    const __hip_bfloat16* __restrict__ ybuf, const int* __restrict__ slots,
    const float* __restrict__ tw, float* __restrict__ out) {
  int t = blockIdx.x * 4 + (threadIdx.x >> 6);
  int lane = threadIdx.x & 63;
  int r0 = slots[t * 2 + 0], r1 = slots[t * 2 + 1];
  float w0 = tw[t * 2 + 0], w1 = tw[t * 2 + 1];
  const short8v* y0 = (const short8v*)(ybuf + (size_t)r0 * HD);
  const short8v* y1 = (const short8v*)(ybuf + (size_t)r1 * HD);
  float4* o = (float4*)(out + (size_t)t * HD);
#pragma unroll
  for (int j = 0; j < 2; j++) {
    int ix = j * 64 + lane;  // 128 short8v per row
    short8v a = y0[ix], b = y1[ix];
    float4 c0, c1;
#pragma unroll
    for (int k = 0; k < 4; k++) {
      float fa = __uint_as_float(((unsigned)(unsigned short)a[k]) << 16);
      float fb = __uint_as_float(((unsigned)(unsigned short)b[k]) << 16);
      ((float*)&c0)[k] = w0 * fa + w1 * fb;
    }
#pragma unroll
    for (int k = 0; k < 4; k++) {
      float fa = __uint_as_float(((unsigned)(unsigned short)a[4 + k]) << 16);
      float fb = __uint_as_float(((unsigned)(unsigned short)b[4 + k]) << 16);
      ((float*)&c1)[k] = w0 * fa + w1 * fb;
    }
    o[ix * 2 + 0] = c0;
    o[ix * 2 + 1] = c1;
  }
}

extern "C" void kernel_launch(void* const* d_in, const int* in_sizes, int n_in,
                              void* d_out, int out_size, void* d_ws, size_t ws_size,
                              hipStream_t stream) {
  (void)in_sizes; (void)n_in; (void)out_size; (void)ws_size;
  const float* h  = (const float*)d_in[0];
  const float* rw = (const float*)d_in[1];
  const float* gw = (const float*)d_in[2];
  const float* uw = (const float*)d_in[3];
  const float* dw = (const float*)d_in[4];
  float* out = (float*)d_out;

  char* ws = (char*)d_ws;
  size_t off = 0;
  auto alloc = [&](size_t bytes) { char* p = ws + off; off += (bytes + 255) & ~255ULL; return p; };
  __hip_bfloat16* wg  = (__hip_bfloat16*)alloc((size_t)NE * ID * HD * 2);
  __hip_bfloat16* wu  = (__hip_bfloat16*)alloc((size_t)NE * ID * HD * 2);
  __hip_bfloat16* wd  = (__hip_bfloat16*)alloc((size_t)NE * HD * ID * 2);
  __hip_bfloat16* act = (__hip_bfloat16*)alloc((size_t)RMAX * ID * 2);
  __hip_bfloat16* hx  = (__hip_bfloat16*)alloc((size_t)TOKENS * HD * 2);
  __hip_bfloat16* ybuf = (__hip_bfloat16*)alloc((size_t)RMAX * HD * 2);
  __hip_bfloat16* zrow = (__hip_bfloat16*)alloc(HD * 2);
  int* rowmap = (int*)alloc(RMAX * 4);
  int* tidx   = (int*)alloc(TOKENS * 2 * 4);
  float* twt  = (float*)alloc(TOKENS * 2 * 4);
  int* slots  = (int*)alloc(TOKENS * 2 * 4);
  int* cnt    = (int*)alloc(256);
  int* cnt2   = (int*)alloc(256);
  int* ofs    = (int*)alloc(256);

  hipMemsetAsync(cnt, 0, NE * 4, stream);
  hipMemsetAsync(rowmap, 0xFF, RMAX * 4, stream);
  hipMemsetAsync(zrow, 0, HD * 2, stream);

  router_conv_kernel<<<RTR_BLOCKS + CVTGU_BLOCKS, 256, 0, stream>>>(
      h, rw, hx, tidx, twt, cnt, gw, uw, wg);
  scan_kernel<<<1, 64, 0, stream>>>(cnt, ofs, cnt2);
  scatter_kernel<<<TOKENS / 256, 256, 0, stream>>>(tidx, ofs, cnt2, rowmap, slots);
  gemm1_kernel<<<NG1 + CVTD_BLOCKS, 512, 0, stream>>>(hx, wg, wu, rowmap, ofs, zrow, act, dw, wd);
  gemm2_kernel<<<GRID2, 512, 0, stream>>>(act, wd, ofs, ybuf);
  combine_kernel<<<TOKENS / 4, 256, 0, stream>>>(ybuf, slots, twt, out);
}

// Round 13
// 826.446 us; speedup vs baseline: 1.0258x; 1.0258x over previous
//
#include <hip/hip_runtime.h>
#include <hip/hip_bf16.h>
#include <math.h>
#include <stdint.h>

// Problem constants (B=4, S=2048, H=1024, I=4096, E=8, K=2)
#define TOKENS 8192
#define HD 1024
#define ID 4096
#define NE 8
#define RMAX 18432   // 16384 + 8*256 worst-case padded rows (experts padded to 256)
#define MAXT 72      // RMAX/256 max M-tiles
#define NG1 2304     // gemm1 gemm blocks (MAXT*32)
#define CVTD_BLOCKS 8192  // convert-Wd tail blocks in gemm1 dispatch (512 thr * 8 elem)
#define RTR_BLOCKS 2048   // router blocks in router_conv dispatch
#define CVTGU_BLOCKS 32768
#define NWG2 576          // gemm2 logical tiles (MAXT*8)
#define GRID2 512         // gemm2 persistent grid

typedef __attribute__((ext_vector_type(8))) short short8v;
typedef __attribute__((ext_vector_type(4))) float f32x4;

typedef const __attribute__((address_space(1))) unsigned int* gas_u32p;
typedef __attribute__((address_space(3))) unsigned int* las_u32p;

__device__ __forceinline__ void stage16(const void* g, void* l) {
  __builtin_amdgcn_global_load_lds((gas_u32p)g, (las_u32p)l, 16, 0, 0);
}

#define BARRIER asm volatile("s_barrier" ::: "memory")
#define WAITLGKM asm volatile("s_waitcnt lgkmcnt(0)" ::: "memory")
#define VMC0 asm volatile("s_waitcnt vmcnt(0)" ::: "memory")
#define VMC6 asm volatile("s_waitcnt vmcnt(6)" ::: "memory")

// convert 8 consecutive fp32 -> 8 bf16 packed in int4 (plain loads; NT hints measured worse)
__device__ __forceinline__ int4 cvt8(const float* __restrict__ src) {
  float4 a = ((const float4*)src)[0];
  float4 b = ((const float4*)src)[1];
  union { __hip_bfloat16 h[8]; int4 v; } u;
  u.h[0] = __float2bfloat16(a.x); u.h[1] = __float2bfloat16(a.y);
  u.h[2] = __float2bfloat16(a.z); u.h[3] = __float2bfloat16(a.w);
  u.h[4] = __float2bfloat16(b.x); u.h[5] = __float2bfloat16(b.y);
  u.h[6] = __float2bfloat16(b.z); u.h[7] = __float2bfloat16(b.w);
  return u.v;
}

// ---------------- router (blocks 0..2047) + convert gate/up (tail blocks) ----------------
__global__ __launch_bounds__(256) void router_conv_kernel(
    const float* __restrict__ h, const float* __restrict__ rw,
    __hip_bfloat16* __restrict__ hx, int* __restrict__ tidx,
    float* __restrict__ tw, int* __restrict__ cnt,
    const float* __restrict__ gw, const float* __restrict__ uw,
    __hip_bfloat16* __restrict__ wgu) {
  if (blockIdx.x >= RTR_BLOCKS) {
    int cb = blockIdx.x - RTR_BLOCKS;       // [0, 32768)
    int r = cb >> 14;                        // 2 regions x 16384 blocks
    const float* src = (r == 0) ? gw : uw;
    __hip_bfloat16* dst = wgu + (size_t)r * ((size_t)NE * ID * HD);
    size_t i = (((size_t)(cb & 16383)) * 256 + threadIdx.x) * 8;
    *(int4*)(dst + i) = cvt8(src + i);
    return;
  }
  int wid = threadIdx.x >> 6, lane = threadIdx.x & 63;
  int t = blockIdx.x * 4 + wid;
  const float4* h4 = (const float4*)(h + (size_t)t * HD);
  float x[16];
  {
    float4 xa = h4[lane * 4 + 0], xb = h4[lane * 4 + 1], xc = h4[lane * 4 + 2], xd = h4[lane * 4 + 3];
    x[0] = xa.x; x[1] = xa.y; x[2] = xa.z; x[3] = xa.w;
    x[4] = xb.x; x[5] = xb.y; x[6] = xb.z; x[7] = xb.w;
    x[8] = xc.x; x[9] = xc.y; x[10] = xc.z; x[11] = xc.w;
    x[12] = xd.x; x[13] = xd.y; x[14] = xd.z; x[15] = xd.w;
  }
  union { __hip_bfloat16 hb[16]; int4 v[2]; } u;
#pragma unroll
  for (int j = 0; j < 16; j++) u.hb[j] = __float2bfloat16(x[j]);
  {
    int4* hxp = (int4*)(hx + (size_t)t * HD + lane * 16);
    hxp[0] = u.v[0]; hxp[1] = u.v[1];
  }
  double acc[NE];
#pragma unroll
  for (int e = 0; e < NE; e++) {
    const float4* w4 = (const float4*)(rw + e * HD);
    float4 wa = w4[lane * 4 + 0], wb = w4[lane * 4 + 1], wc = w4[lane * 4 + 2], wd = w4[lane * 4 + 3];
    double s = 0.0;
    s += (double)x[0] * wa.x + (double)x[1] * wa.y + (double)x[2] * wa.z + (double)x[3] * wa.w;
    s += (double)x[4] * wb.x + (double)x[5] * wb.y + (double)x[6] * wb.z + (double)x[7] * wb.w;
    s += (double)x[8] * wc.x + (double)x[9] * wc.y + (double)x[10] * wc.z + (double)x[11] * wc.w;
    s += (double)x[12] * wd.x + (double)x[13] * wd.y + (double)x[14] * wd.z + (double)x[15] * wd.w;
    acc[e] = s;
  }
#pragma unroll
  for (int off = 32; off >= 1; off >>= 1)
#pragma unroll
    for (int e = 0; e < NE; e++) acc[e] += __shfl_xor(acc[e], off, 64);
  if (lane == 0) {
    int i0 = 0; double l0 = acc[0];
#pragma unroll
    for (int e = 1; e < NE; e++) if (acc[e] > l0) { l0 = acc[e]; i0 = e; }
    int i1 = -1; double l1 = -1.0e300;
#pragma unroll
    for (int e = 0; e < NE; e++) if (e != i0 && acc[e] > l1) { l1 = acc[e]; i1 = e; }
    double r = exp(l1 - l0);  // <= 1
    float w0 = (float)(1.0 / (1.0 + r));
    float w1 = (float)(r / (1.0 + r));
    tidx[t * 2 + 0] = i0; tidx[t * 2 + 1] = i1;
    tw[t * 2 + 0] = w0;  tw[t * 2 + 1] = w1;
    atomicAdd(&cnt[i0], 1); atomicAdd(&cnt[i1], 1);
  }
}

// ---------------- offsets scan (pad each expert to 256 rows) ----------------
__global__ void scan_kernel(const int* __restrict__ cnt, int* __restrict__ ofs, int* __restrict__ cnt2) {
  if (threadIdx.x == 0) {
    int a = 0;
    for (int e = 0; e < NE; e++) { ofs[e] = a; a += (cnt[e] + 255) & ~255; }
    ofs[NE] = a;
  }
  if (threadIdx.x < NE) cnt2[threadIdx.x] = 0;
}

// ---------------- scatter token -> expert row lists (+ slot map) ----------------
__global__ __launch_bounds__(256) void scatter_kernel(
    const int* __restrict__ tidx, const int* __restrict__ ofs, int* __restrict__ cnt2,
    int* __restrict__ rowmap, int* __restrict__ slots) {
  int t = blockIdx.x * 256 + threadIdx.x;
#pragma unroll
  for (int k = 0; k < 2; k++) {
    int e = tidx[t * 2 + k];
    int pos = atomicAdd(&cnt2[e], 1);
    int row = ofs[e] + pos;
    rowmap[row] = t;
    slots[t * 2 + k] = row;
  }
}

// MFMA quadrant: 4 m-frags x 2 n-frags x 2 kk = 16 MFMA
#define MFMAQ(ACC, MO, NO, AF, BF)                                                         \
  { _Pragma("unroll") for (int m_ = 0; m_ < 4; m_++)                                       \
    _Pragma("unroll") for (int n_ = 0; n_ < 2; n_++)                                       \
    _Pragma("unroll") for (int k_ = 0; k_ < 2; k_++)                                       \
      ACC[(MO) + m_][(NO) + n_] = __builtin_amdgcn_mfma_f32_16x16x32_bf16(                 \
          AF[m_][k_], BF[n_][k_], ACC[(MO) + m_][(NO) + n_], 0, 0, 0); }

// 16 MFMA, one k-half: 4m x 4n
#define MFMA16K(ACC, AF, BF)                                                               \
  { _Pragma("unroll") for (int m_ = 0; m_ < 4; m_++)                                       \
    _Pragma("unroll") for (int n_ = 0; n_ < 4; n_++)                                       \
      ACC[m_][n_] = __builtin_amdgcn_mfma_f32_16x16x32_bf16(                               \
          AF[m_], BF[n_], ACC[m_][n_], 0, 0, 0); }

// =================== GEMM1 (fused gate+up+silu), 256x128 tile, 8-phase ===================
// R8-proven (best measured). tm-fastest tile order; Wd-convert tail blocks.
__global__ __launch_bounds__(512, 2) void gemm1_kernel(
    const __hip_bfloat16* __restrict__ hx, const __hip_bfloat16* __restrict__ Wg,
    const __hip_bfloat16* __restrict__ Wu, const int* __restrict__ rowmap,
    const int* __restrict__ ofs, const __hip_bfloat16* __restrict__ zrow,
    __hip_bfloat16* __restrict__ act,
    const float* __restrict__ dwsrc, __hip_bfloat16* __restrict__ wd) {
  const int tid = threadIdx.x;
  if (blockIdx.x >= NG1) {
    size_t i = (((size_t)(blockIdx.x - NG1)) * 512 + tid) * 8;
    *(int4*)(wd + i) = cvt8(dwsrc + i);
    return;
  }
  __shared__ __align__(128) char lds[131072];
  int wg0 = blockIdx.x;
  int wg = (wg0 & 7) * (NG1 >> 3) + (wg0 >> 3);  // XCD-chunked swizzle
  const int tm = wg % MAXT, tn = wg / MAXT;      // tm-fastest: chunk shares weights
  const int Rtot = ofs[NE];
  const int row0 = tm * 256;
  if (row0 >= Rtot) return;
  int e = 0;
#pragma unroll
  for (int i = 1; i < NE; i++) e += (row0 >= ofs[i]);
  const int wid = tid >> 6, lane = tid & 63;
  const int wm = wid >> 1, wn = wid & 1;  // 4 M-warps x 2 N-warps
  const int fr = lane & 15, fkE = (lane >> 4) << 3;
  const int wmB = wm * 64, wnB = wn * 64;

  const char* srcA[4]; const char* srcG[2]; const char* srcU[2];
  int ldA[4], ldG[2], ldU[2];
#pragma unroll
  for (int j = 0; j < 4; j++) {
    int d = j * 8192 + tid * 16;
    int row = d >> 7;
    int kb = (d ^ (((d >> 7) & 7) << 4)) & 127;
    int tok = rowmap[row0 + row];
    const __hip_bfloat16* base = (tok >= 0) ? (hx + (size_t)tok * HD) : zrow;
    srcA[j] = (const char*)base + kb;
    ldA[j] = j * 8192 + wid * 1024;
  }
#pragma unroll
  for (int j = 0; j < 2; j++) {
    int d = j * 8192 + tid * 16;
    int row = d >> 7;
    int kb = (d ^ (((d >> 7) & 7) << 4)) & 127;
    srcG[j] = (const char*)(Wg + ((size_t)e * ID + tn * 128 + row) * HD) + kb;
    srcU[j] = (const char*)(Wu + ((size_t)e * ID + tn * 128 + row) * HD) + kb;
    ldG[j] = 32768 + j * 8192 + wid * 1024;
    ldU[j] = 49152 + j * 8192 + wid * 1024;
  }
#define STG_A(j, t, bf) stage16(srcA[j] + (size_t)(t) * 128, (char*)lds + (bf) * 65536 + ldA[j])
#define STG_G(j, t, bf) stage16(srcG[j] + (size_t)(t) * 128, (char*)lds + (bf) * 65536 + ldG[j])
#define STG_U(j, t, bf) stage16(srcU[j] + (size_t)(t) * 128, (char*)lds + (bf) * 65536 + ldU[j])

  auto RD = [&](int bf, int poff, int rowi, int kki) -> short8v {
    int o = ((rowi + fr) << 7) + ((kki << 5) + fkE) * 2;
    o ^= ((o >> 7) & 7) << 4;
    return *(const short8v*)(&lds[bf * 65536 + poff + o]);
  };

  f32x4 accG[4][4], accU[4][4];
#pragma unroll
  for (int m = 0; m < 4; m++)
#pragma unroll
    for (int n = 0; n < 4; n++) { accG[m][n] = (f32x4)(0.0f); accU[m][n] = (f32x4)(0.0f); }

  const int NT = HD / 64;  // 16 K-tiles
#pragma unroll
  for (int j = 0; j < 4; j++) STG_A(j, 0, 0);
#pragma unroll
  for (int j = 0; j < 2; j++) STG_G(j, 0, 0);
#pragma unroll
  for (int j = 0; j < 2; j++) STG_U(j, 0, 0);
#pragma unroll
  for (int j = 0; j < 4; j++) STG_A(j, 1, 1);
#pragma unroll
  for (int j = 0; j < 2; j++) STG_G(j, 1, 1);
  VMC6; BARRIER;

#pragma unroll 1
  for (int I = 0; I < NT / 2; ++I) {
    const int t0 = 2 * I;
    const bool more = (t0 + 2 < NT);
    short8v a[4][2], bA[2][2], bB[2][2];
    // P1
#pragma unroll
    for (int m = 0; m < 4; m++) { a[m][0] = RD(0, 0, wmB + m * 16, 0); a[m][1] = RD(0, 0, wmB + m * 16, 1); }
#pragma unroll
    for (int n = 0; n < 2; n++) { bA[n][0] = RD(0, 32768, wnB + n * 16, 0); bA[n][1] = RD(0, 32768, wnB + n * 16, 1); }
    STG_U(0, t0 + 1, 1); STG_U(1, t0 + 1, 1);
    BARRIER; WAITLGKM;
    __builtin_amdgcn_s_setprio(1); MFMAQ(accG, 0, 0, a, bA); __builtin_amdgcn_s_setprio(0);
    BARRIER;
    // P2
#pragma unroll
    for (int n = 0; n < 2; n++) { bB[n][0] = RD(0, 32768, wnB + 32 + n * 16, 0); bB[n][1] = RD(0, 32768, wnB + 32 + n * 16, 1); }
    if (more) { STG_A(0, t0 + 2, 0); STG_A(1, t0 + 2, 0); }
    BARRIER; WAITLGKM;
    __builtin_amdgcn_s_setprio(1); MFMAQ(accG, 0, 2, a, bB); __builtin_amdgcn_s_setprio(0);
    BARRIER;
    // P3
#pragma unroll
    for (int n = 0; n < 2; n++) { bA[n][0] = RD(0, 49152, wnB + n * 16, 0); bA[n][1] = RD(0, 49152, wnB + n * 16, 1); }
    if (more) { STG_A(2, t0 + 2, 0); STG_A(3, t0 + 2, 0); }
    BARRIER; WAITLGKM;
    __builtin_amdgcn_s_setprio(1); MFMAQ(accU, 0, 0, a, bA); __builtin_amdgcn_s_setprio(0);
    BARRIER;
    // P4
#pragma unroll
    for (int n = 0; n < 2; n++) { bB[n][0] = RD(0, 49152, wnB + 32 + n * 16, 0); bB[n][1] = RD(0, 49152, wnB + 32 + n * 16, 1); }
    if (more) { STG_G(0, t0 + 2, 0); STG_G(1, t0 + 2, 0); }
    BARRIER; WAITLGKM;
    __builtin_amdgcn_s_setprio(1); MFMAQ(accU, 0, 2, a, bB); __builtin_amdgcn_s_setprio(0);
    if (more) { VMC6; } else { VMC0; }
    BARRIER;
    // P5
#pragma unroll
    for (int m = 0; m < 4; m++) { a[m][0] = RD(1, 0, wmB + m * 16, 0); a[m][1] = RD(1, 0, wmB + m * 16, 1); }
#pragma unroll
    for (int n = 0; n < 2; n++) { bA[n][0] = RD(1, 32768, wnB + n * 16, 0); bA[n][1] = RD(1, 32768, wnB + n * 16, 1); }
    if (more) { STG_U(0, t0 + 2, 0); STG_U(1, t0 + 2, 0); }
    BARRIER; WAITLGKM;
    __builtin_amdgcn_s_setprio(1); MFMAQ(accG, 0, 0, a, bA); __builtin_amdgcn_s_setprio(0);
    BARRIER;
    // P6
#pragma unroll
    for (int n = 0; n < 2; n++) { bB[n][0] = RD(1, 32768, wnB + 32 + n * 16, 0); bB[n][1] = RD(1, 32768, wnB + 32 + n * 16, 1); }
    if (more) { STG_A(0, t0 + 3, 1); STG_A(1, t0 + 3, 1); }
    BARRIER; WAITLGKM;
    __builtin_amdgcn_s_setprio(1); MFMAQ(accG, 0, 2, a, bB); __builtin_amdgcn_s_setprio(0);
    BARRIER;
    // P7
#pragma unroll
    for (int n = 0; n < 2; n++) { bA[n][0] = RD(1, 49152, wnB + n * 16, 0); bA[n][1] = RD(1, 49152, wnB + n * 16, 1); }
    if (more) { STG_A(2, t0 + 3, 1); STG_A(3, t0 + 3, 1); }
    BARRIER; WAITLGKM;
    __builtin_amdgcn_s_setprio(1); MFMAQ(accU, 0, 0, a, bA); __builtin_amdgcn_s_setprio(0);
    BARRIER;
    // P8
#pragma unroll
    for (int n = 0; n < 2; n++) { bB[n][0] = RD(1, 49152, wnB + 32 + n * 16, 0); bB[n][1] = RD(1, 49152, wnB + 32 + n * 16, 1); }
    if (more) { STG_G(0, t0 + 3, 1); STG_G(1, t0 + 3, 1); }
    BARRIER; WAITLGKM;
    __builtin_amdgcn_s_setprio(1); MFMAQ(accU, 0, 2, a, bB); __builtin_amdgcn_s_setprio(0);
    if (more) { VMC6; } else { VMC0; }
    BARRIER;
  }
#undef STG_A
#undef STG_G
#undef STG_U

  // epilogue: act = bf16(silu(g)*u)
  const int rb = row0 + wmB + ((lane >> 4) << 2);
  const int cb = tn * 128 + wnB + fr;
#pragma unroll
  for (int m = 0; m < 4; m++)
#pragma unroll
    for (int i = 0; i < 4; i++) {
      int r = rb + m * 16 + i;
      __hip_bfloat16* dst = act + (size_t)r * ID + cb;
#pragma unroll
      for (int n = 0; n < 4; n++) {
        float g = accG[m][n][i], uu = accU[m][n][i];
        float s = g / (1.0f + __expf(-g));
        dst[n * 16] = __float2bfloat16(s * uu);
      }
    }
}

// =================== GEMM2: y = act @ Wd[e]^T, 256x128, 3-buffer, PERSISTENT, bf16 out ===
__global__ __launch_bounds__(512, 2) void gemm2_kernel(
    const __hip_bfloat16* __restrict__ act, const __hip_bfloat16* __restrict__ Wd,
    const int* __restrict__ ofs, __hip_bfloat16* __restrict__ ybuf) {
  __shared__ __align__(128) char lds[147456];
  const int tid = threadIdx.x, wid = tid >> 6, lane = tid & 63;
  const int wm = wid >> 1, wn = wid & 1;
  const int fr = lane & 15, fkE = (lane >> 4) << 3;
  const int wmB = wm * 64, wnB = wn * 64;
  const int Rtot = ofs[NE];

  auto RD = [&](const char* base, int poff, int rowi, int kki) -> short8v {
    int o = ((rowi + fr) << 7) + ((kki << 5) + fkE) * 2;
    o ^= ((o >> 7) & 7) << 4;
    return *(const short8v*)(base + poff + o);
  };

#pragma unroll 1
  for (int wgl = blockIdx.x; wgl < NWG2; wgl += GRID2) {
    int wg = (wgl & 7) * (NWG2 >> 3) + (wgl >> 3);  // XCD-chunked swizzle
    const int tm = wg >> 3, tn = wg & 7;
    const int row0 = tm * 256;
    if (row0 >= Rtot) continue;
    int e = 0;
#pragma unroll
    for (int i = 1; i < NE; i++) e += (row0 >= ofs[i]);

    const char* srcA[4]; const char* srcB[2];
    int ldA[4], ldB[2];
#pragma unroll
    for (int j = 0; j < 4; j++) {
      int d = j * 8192 + tid * 16;
      int row = d >> 7;
      int kb = (d ^ (((d >> 7) & 7) << 4)) & 127;
      srcA[j] = (const char*)(act + (size_t)(row0 + row) * ID) + kb;
      ldA[j] = j * 8192 + wid * 1024;
    }
#pragma unroll
    for (int j = 0; j < 2; j++) {
      int d = j * 8192 + tid * 16;
      int row = d >> 7;
      int kb = (d ^ (((d >> 7) & 7) << 4)) & 127;
      srcB[j] = (const char*)(Wd + ((size_t)e * HD + tn * 128 + row) * ID) + kb;
      ldB[j] = 32768 + j * 8192 + wid * 1024;
    }
#define STG_A2(j, t, q) stage16(srcA[j] + (size_t)(t) * 128, (char*)lds + (q) * 49152 + ldA[j])
#define STG_B2(j, t, q) stage16(srcB[j] + (size_t)(t) * 128, (char*)lds + (q) * 49152 + ldB[j])

    f32x4 acc[4][4];
#pragma unroll
    for (int m = 0; m < 4; m++)
#pragma unroll
      for (int n = 0; n < 4; n++) acc[m][n] = (f32x4)(0.0f);

    const int NT = ID / 64;  // 64 K-tiles
#pragma unroll
    for (int j = 0; j < 4; j++) STG_A2(j, 0, 0);
    STG_B2(0, 0, 0); STG_B2(1, 0, 0);
#pragma unroll
    for (int j = 0; j < 4; j++) STG_A2(j, 1, 1);
    STG_B2(0, 1, 1); STG_B2(1, 1, 1);
    VMC6; BARRIER;

    int q = 0;
#pragma unroll 1
    for (int T = 0; T < NT; ++T) {
      const bool more = (T + 2 < NT);
      const int sq = (q >= 1) ? (q - 1) : 2;  // (q+2)%3
      const char* base = (const char*)lds + q * 49152;
      short8v a0[4], b0[4], a1[4], b1[4];
#pragma unroll
      for (int m = 0; m < 4; m++) a0[m] = RD(base, 0, wmB + m * 16, 0);
#pragma unroll
      for (int n = 0; n < 4; n++) b0[n] = RD(base, 32768, wnB + n * 16, 0);
      if (more) { STG_A2(0, T + 2, sq); STG_A2(1, T + 2, sq); STG_A2(2, T + 2, sq); }
      BARRIER; WAITLGKM;
      __builtin_amdgcn_s_setprio(1); MFMA16K(acc, a0, b0); __builtin_amdgcn_s_setprio(0);
      BARRIER;
#pragma unroll
      for (int m = 0; m < 4; m++) a1[m] = RD(base, 0, wmB + m * 16, 1);
#pragma unroll
      for (int n = 0; n < 4; n++) b1[n] = RD(base, 32768, wnB + n * 16, 1);
      if (more) { STG_A2(3, T + 2, sq); STG_B2(0, T + 2, sq); STG_B2(1, T + 2, sq); }
      BARRIER; WAITLGKM;
      __builtin_amdgcn_s_setprio(1); MFMA16K(acc, a1, b1); __builtin_amdgcn_s_setprio(0);
      if (more) { VMC6; } else { VMC0; }
      BARRIER;
      q = (q == 2) ? 0 : (q + 1);
    }
#undef STG_A2
#undef STG_B2

    const int rb = row0 + wmB + ((lane >> 4) << 2);
    const int cb = tn * 128 + wnB + fr;
#pragma unroll
    for (int m = 0; m < 4; m++)
#pragma unroll
      for (int i = 0; i < 4; i++) {
        int r = rb + m * 16 + i;
        __hip_bfloat16* dst = ybuf + (size_t)r * HD + cb;
#pragma unroll
        for (int n = 0; n < 4; n++) dst[n * 16] = __float2bfloat16(acc[m][n][i]);
      }
    BARRIER;  // LDS safe before next persistent tile's prologue
  }
}

// ---------------- combine: out[t] = w0*y[slot0] + w1*y[slot1] (bf16 y) ----------------
__global__ __launch_bounds__(256) void combine_kernel(
    const __hip_bfloat16* __restrict__ ybuf, const int* __restrict__ slots,
    const float* __restrict__ tw, float* __restrict__ out) {
  int t = blockIdx.x * 4 + (threadIdx.x >> 6);
  int lane = threadIdx.x & 63;
  int r0 = slots[t * 2 + 0], r1 = slots[t * 2 + 1];
  float w0 = tw[t * 2 + 0], w1 = tw[t * 2 + 1];
  const short8v* y0 = (const short8v*)(ybuf + (size_t)r0 * HD);
  const short8v* y1 = (const short8v*)(ybuf + (size_t)r1 * HD);
  float4* o = (float4*)(out + (size_t)t * HD);
#pragma unroll
  for (int j = 0; j < 2; j++) {
    int ix = j * 64 + lane;  // 128 short8v per row
    short8v a = y0[ix], b = y1[ix];
    float4 c0, c1;
#pragma unroll
    for (int k = 0; k < 4; k++) {
      float fa = __uint_as_float(((unsigned)(unsigned short)a[k]) << 16);
      float fb = __uint_as_float(((unsigned)(unsigned short)b[k]) << 16);
      ((float*)&c0)[k] = w0 * fa + w1 * fb;
    }
#pragma unroll
    for (int k = 0; k < 4; k++) {
      float fa = __uint_as_float(((unsigned)(unsigned short)a[4 + k]) << 16);
      float fb = __uint_as_float(((unsigned)(unsigned short)b[4 + k]) << 16);
      ((float*)&c1)[k] = w0 * fa + w1 * fb;
    }
    o[ix * 2 + 0] = c0;
    o[ix * 2 + 1] = c1;
  }
}

extern "C" void kernel_launch(void* const* d_in, const int* in_sizes, int n_in,
                              void* d_out, int out_size, void* d_ws, size_t ws_size,
                              hipStream_t stream) {
  (void)in_sizes; (void)n_in; (void)out_size; (void)ws_size;
  const float* h  = (const float*)d_in[0];
  const float* rw = (const float*)d_in[1];
  const float* gw = (const float*)d_in[2];
  const float* uw = (const float*)d_in[3];
  const float* dw = (const float*)d_in[4];
  float* out = (float*)d_out;

  char* ws = (char*)d_ws;
  size_t off = 0;
  auto alloc = [&](size_t bytes) { char* p = ws + off; off += (bytes + 255) & ~255ULL; return p; };
  __hip_bfloat16* wg  = (__hip_bfloat16*)alloc((size_t)NE * ID * HD * 2);
  __hip_bfloat16* wu  = (__hip_bfloat16*)alloc((size_t)NE * ID * HD * 2);
  __hip_bfloat16* wd  = (__hip_bfloat16*)alloc((size_t)NE * HD * ID * 2);
  __hip_bfloat16* act = (__hip_bfloat16*)alloc((size_t)RMAX * ID * 2);
  __hip_bfloat16* hx  = (__hip_bfloat16*)alloc((size_t)TOKENS * HD * 2);
  __hip_bfloat16* ybuf = (__hip_bfloat16*)alloc((size_t)RMAX * HD * 2);
  __hip_bfloat16* zrow = (__hip_bfloat16*)alloc(HD * 2);
  int* rowmap = (int*)alloc(RMAX * 4);
  int* tidx   = (int*)alloc(TOKENS * 2 * 4);
  float* twt  = (float*)alloc(TOKENS * 2 * 4);
  int* slots  = (int*)alloc(TOKENS * 2 * 4);
  int* cnt    = (int*)alloc(256);
  int* cnt2   = (int*)alloc(256);
  int* ofs    = (int*)alloc(256);

  hipMemsetAsync(cnt, 0, NE * 4, stream);
  hipMemsetAsync(rowmap, 0xFF, RMAX * 4, stream);
  hipMemsetAsync(zrow, 0, HD * 2, stream);

  router_conv_kernel<<<RTR_BLOCKS + CVTGU_BLOCKS, 256, 0, stream>>>(
      h, rw, hx, tidx, twt, cnt, gw, uw, wg);
  scan_kernel<<<1, 64, 0, stream>>>(cnt, ofs, cnt2);
  scatter_kernel<<<TOKENS / 256, 256, 0, stream>>>(tidx, ofs, cnt2, rowmap, slots);
  gemm1_kernel<<<NG1 + CVTD_BLOCKS, 512, 0, stream>>>(hx, wg, wu, rowmap, ofs, zrow, act, dw, wd);
  gemm2_kernel<<<GRID2, 512, 0, stream>>>(act, wd, ofs, ybuf);
  combine_kernel<<<TOKENS / 4, 256, 0, stream>>>(ybuf, slots, twt, out);
}